// Round 4
// baseline (960.426 us; speedup 1.0000x reference)
//
#include <hip/hip_runtime.h>
#include <hip/hip_fp16.h>

#define NU 100000
#define NI 50000
#define NB 1000
#define NN 151000          // total nodes
#define NE 4800000
#define KDIM 448

#define BROWS 512                       // rows per scan block
#define NBK ((NN + BROWS - 1) / BROWS)  // 295 scan blocks

typedef float v2f __attribute__((ext_vector_type(2)));

// pack 4 floats -> 4x fp8 e4m3 (OCP on gfx950) in one dword
__device__ __forceinline__ unsigned int pk_fp8x4(float a, float b, float c, float d) {
  int r = 0;
  r = __builtin_amdgcn_cvt_pk_fp8_f32(a, b, r, false);  // low 16
  r = __builtin_amdgcn_cvt_pk_fp8_f32(c, d, r, true);   // high 16
  return (unsigned int)r;
}

// ================= Phase A: per-row histogram (global atomics, L2-resident) =================
#define RH_EPT 8
__global__ __launch_bounds__(256) void row_hist(const int* __restrict__ erow,
                                                int* __restrict__ rcnt) {
  int base = blockIdx.x * (256 * RH_EPT) + threadIdx.x;
#pragma unroll
  for (int j = 0; j < RH_EPT; ++j) {
    int e = base + j * 256;
    if (e < NE) atomicAdd(&rcnt[erow[e]], 1);
  }
}

// ================= Phase B1: per-512-row partial sums =================
__global__ __launch_bounds__(256) void bucket_sum(const int* __restrict__ rcnt,
                                                  int* __restrict__ bcnt) {
  __shared__ int sh[256];
  int b = blockIdx.x;
  int tid = threadIdx.x;
  int i = b * BROWS + 2 * tid;
  int s = 0;
  if (i < NN) s += rcnt[i];
  if (i + 1 < NN) s += rcnt[i + 1];
  sh[tid] = s;
  __syncthreads();
  for (int off = 128; off > 0; off >>= 1) {
    if (tid < off) sh[tid] += sh[tid + off];
    __syncthreads();
  }
  if (tid == 0) bcnt[b] = sh[0];
}

// ================= Phase B2: scan 295 partial sums (single block) =================
__global__ __launch_bounds__(256) void bucket_scan(const int* __restrict__ bcnt,
                                                   int* __restrict__ bstart,
                                                   int* __restrict__ rp) {
  __shared__ int sh[256];
  int tid = threadIdx.x;
  int v[2];
  int s = 0;
#pragma unroll
  for (int j = 0; j < 2; ++j) {
    int i = tid * 2 + j;
    v[j] = (i < NBK) ? bcnt[i] : 0;
    s += v[j];
  }
  sh[tid] = s;
  __syncthreads();
  for (int off = 1; off < 256; off <<= 1) {
    int t = (tid >= off) ? sh[tid - off] : 0;
    __syncthreads();
    sh[tid] += t;
    __syncthreads();
  }
  int run = sh[tid] - s;  // exclusive
#pragma unroll
  for (int j = 0; j < 2; ++j) {
    int i = tid * 2 + j;
    if (i < NBK) bstart[i] = run;
    run += v[j];
  }
  if (tid == 255) {
    bstart[NBK] = NE;
    rp[NN] = NE;
  }
}

// ================= Phase B3: per-512-row scan + offset -> rp =================
__global__ __launch_bounds__(256) void row_scan(const int* __restrict__ rcnt,
                                                const int* __restrict__ bstart,
                                                int* __restrict__ rp) {
  __shared__ int sh[256];
  int b = blockIdx.x;
  int tid = threadIdx.x;
  int i0 = b * BROWS + 2 * tid;
  int v0 = (i0 < NN) ? rcnt[i0] : 0;
  int v1 = (i0 + 1 < NN) ? rcnt[i0 + 1] : 0;
  int s = v0 + v1;
  sh[tid] = s;
  __syncthreads();
  for (int off = 1; off < 256; off <<= 1) {
    int t = (tid >= off) ? sh[tid - off] : 0;
    __syncthreads();
    sh[tid] += t;
    __syncthreads();
  }
  int excl = sh[tid] - s + bstart[b];
  if (i0 < NN) rp[i0] = excl;
  if (i0 + 1 < NN) rp[i0 + 1] = excl + v0;
}

// ================= Phase C: direct scatter into CSR slots =================
// Full-occupancy latency hiding: 2344 blocks (~9/CU). Within-row order is
// arrival order (sum is commutative; tolerance absorbs it).
#define RS_EPT 8
__global__ __launch_bounds__(256) void row_scatter(
    const int* __restrict__ erow, const int* __restrict__ ecol,
    const float* __restrict__ eval, const int* __restrict__ rp,
    int* __restrict__ gfill, int2* __restrict__ cv) {
  int base = blockIdx.x * (256 * RS_EPT) + threadIdx.x;
#pragma unroll
  for (int j = 0; j < RS_EPT; ++j) {
    int e = base + j * 256;
    if (e < NE) {
      int r = erow[e];
      int p = rp[r] + atomicAdd(&gfill[r], 1);
      cv[p] = make_int2(ecol[e], __float_as_int(eval[e]));
    }
  }
}

// ======= fusion GEMM: [NI x 448] @ W^T + bias + leaky; writes fp32 acc-seed + fp8 x =======
__global__ __launch_bounds__(256) void fusion_kernel(
    const float* __restrict__ id_emb, const float* __restrict__ content,
    const float* __restrict__ W, const float* __restrict__ bias,
    unsigned char* __restrict__ x8, float* __restrict__ out) {
  __shared__ float As[16][68];
  __shared__ float Ws[16][68];
  int tid = threadIdx.x;
  int tx = tid & 15;
  int ty = tid >> 4;
  int itemBase = blockIdx.x * 64;
  float acc[4][4] = {};

  int it = tid >> 2;
  int kq = (tid & 3) * 4;

  for (int kb = 0; kb < KDIM; kb += 16) {
    int k = kb + kq;
    int item = itemBase + it;
    int itemc = item < NI ? item : NI - 1;
    float4 a;
    if (k < 64)
      a = *(const float4*)&id_emb[(size_t)itemc * 64 + k];
    else
      a = *(const float4*)&content[(size_t)itemc * 384 + (k - 64)];
    As[kq + 0][it] = a.x; As[kq + 1][it] = a.y; As[kq + 2][it] = a.z; As[kq + 3][it] = a.w;
    float4 w = *(const float4*)&W[(size_t)it * KDIM + k];
    Ws[kq + 0][it] = w.x; Ws[kq + 1][it] = w.y; Ws[kq + 2][it] = w.z; Ws[kq + 3][it] = w.w;
    __syncthreads();
#pragma unroll
    for (int kk = 0; kk < 16; ++kk) {
      float4 af = *(float4*)&As[kk][ty * 4];
      float4 wf = *(float4*)&Ws[kk][tx * 4];
      float av[4] = {af.x, af.y, af.z, af.w};
      float wv[4] = {wf.x, wf.y, wf.z, wf.w};
#pragma unroll
      for (int m = 0; m < 4; ++m)
#pragma unroll
        for (int n = 0; n < 4; ++n) acc[m][n] += av[m] * wv[n];
    }
    __syncthreads();
  }

  int d0 = tx * 4;
  float4 bb = *(const float4*)&bias[d0];
#pragma unroll
  for (int m = 0; m < 4; ++m) {
    int item = itemBase + ty * 4 + m;
    if (item >= NI) continue;
    float4 o;
    float t;
    t = acc[m][0] + bb.x; o.x = t >= 0.f ? t : 0.01f * t;
    t = acc[m][1] + bb.y; o.y = t >= 0.f ? t : 0.01f * t;
    t = acc[m][2] + bb.z; o.z = t >= 0.f ? t : 0.01f * t;
    t = acc[m][3] + bb.w; o.w = t >= 0.f ? t : 0.01f * t;
    size_t ofs = (size_t)(NU + item) * 64 + d0;
    *(float4*)&out[ofs] = o;                       // fp32 acc seed
    *(unsigned int*)&x8[ofs] = pk_fp8x4(o.x, o.y, o.z, o.w);
  }
}

// ======= seed: user/brand -> acc seed + fp8 x; user/item passthrough copies =======
#define UN (NU * 64)     // 6400000
#define BN (NB * 64)     // 64000
#define IEL (NI * 64)    // 3200000
__global__ __launch_bounds__(256) void seed_kernel(
    const float* __restrict__ user_emb, const float* __restrict__ brand,
    const float* __restrict__ item_id, unsigned char* __restrict__ x8,
    float* __restrict__ out) {
  int idx = (blockIdx.x * 256 + threadIdx.x) * 4;
  if (idx < UN) {
    float4 f = *(const float4*)&user_emb[idx];
    *(float4*)&out[idx] = f;                         // acc seed
    *(float4*)&out[(size_t)NN * 64 + idx] = f;       // user passthrough
    *(unsigned int*)&x8[idx] = pk_fp8x4(f.x, f.y, f.z, f.w);
  } else if (idx < UN + BN) {
    int k = idx - UN;
    float4 f = *(const float4*)&brand[k];
    int o = (NU + NI) * 64 + k;
    *(float4*)&out[o] = f;                           // acc seed
    *(unsigned int*)&x8[o] = pk_fp8x4(f.x, f.y, f.z, f.w);
  } else if (idx < UN + BN + IEL) {
    int k = idx - (UN + BN);
    float4 f = *(const float4*)&item_id[k];
    *(float4*)&out[(size_t)(NN + NU) * 64 + k] = f;  // item_id passthrough
  }
}

// ======= SpMM: 1 wave/row, 4x16-lane groups, 4B fp8 gathers (64B/edge) =======
template <bool FINAL>
__global__ __launch_bounds__(256) void spmm_kernel(
    const int* __restrict__ rp, const int2* __restrict__ cv,
    const unsigned char* __restrict__ x, unsigned char* __restrict__ y,
    float* __restrict__ acc) {
  int wid = blockIdx.x * 4 + (threadIdx.x >> 6);
  if (wid >= NN) return;
  int lane = threadIdx.x & 63;
  int grp = lane >> 4;          // 0..3: edge group (stride-4 edge walk)
  int d0 = (lane & 15) << 2;    // 4 dims owned per lane
  const unsigned char* __restrict__ xb = x + d0;
  int beg = rp[wid], end = rp[wid + 1];
  float a0 = 0.f, a1 = 0.f, a2 = 0.f, a3 = 0.f;
  float b0 = 0.f, b1 = 0.f, b2 = 0.f, b3 = 0.f;
  int j = beg + grp;
  // main: 4 edges per group per iter (16 edges/wave); cv[j] is 16-lane-uniform
  // -> single broadcast request; gather is 4B/lane = 64B/row segment.
  for (; j + 12 < end; j += 16) {
    int2 p0 = cv[j];
    int2 p1 = cv[j + 4];
    int2 p2 = cv[j + 8];
    int2 p3 = cv[j + 12];
    unsigned int h0 = *(const unsigned int*)(xb + ((size_t)p0.x << 6));
    unsigned int h1 = *(const unsigned int*)(xb + ((size_t)p1.x << 6));
    unsigned int h2 = *(const unsigned int*)(xb + ((size_t)p2.x << 6));
    unsigned int h3 = *(const unsigned int*)(xb + ((size_t)p3.x << 6));
    float v0 = __int_as_float(p0.y);
    float v1 = __int_as_float(p1.y);
    float v2 = __int_as_float(p2.y);
    float v3 = __int_as_float(p3.y);
    v2f f;
    f = __builtin_amdgcn_cvt_pk_f32_fp8(h0, false); a0 += v0 * f.x; a1 += v0 * f.y;
    f = __builtin_amdgcn_cvt_pk_f32_fp8(h0, true);  a2 += v0 * f.x; a3 += v0 * f.y;
    f = __builtin_amdgcn_cvt_pk_f32_fp8(h1, false); b0 += v1 * f.x; b1 += v1 * f.y;
    f = __builtin_amdgcn_cvt_pk_f32_fp8(h1, true);  b2 += v1 * f.x; b3 += v1 * f.y;
    f = __builtin_amdgcn_cvt_pk_f32_fp8(h2, false); a0 += v2 * f.x; a1 += v2 * f.y;
    f = __builtin_amdgcn_cvt_pk_f32_fp8(h2, true);  a2 += v2 * f.x; a3 += v2 * f.y;
    f = __builtin_amdgcn_cvt_pk_f32_fp8(h3, false); b0 += v3 * f.x; b1 += v3 * f.y;
    f = __builtin_amdgcn_cvt_pk_f32_fp8(h3, true);  b2 += v3 * f.x; b3 += v3 * f.y;
  }
  for (; j < end; j += 4) {  // tail: <=3 iters per group
    int2 p = cv[j];
    unsigned int h = *(const unsigned int*)(xb + ((size_t)p.x << 6));
    float v = __int_as_float(p.y);
    v2f f;
    f = __builtin_amdgcn_cvt_pk_f32_fp8(h, false); a0 += v * f.x; a1 += v * f.y;
    f = __builtin_amdgcn_cvt_pk_f32_fp8(h, true);  a2 += v * f.x; a3 += v * f.y;
  }
  a0 += b0; a1 += b1; a2 += b2; a3 += b3;
  // reduce the 4 groups (epilogue only)
  a0 += __shfl_xor(a0, 16); a1 += __shfl_xor(a1, 16);
  a2 += __shfl_xor(a2, 16); a3 += __shfl_xor(a3, 16);
  a0 += __shfl_xor(a0, 32); a1 += __shfl_xor(a1, 32);
  a2 += __shfl_xor(a2, 32); a3 += __shfl_xor(a3, 32);
  if (lane < 16) {
    int o = (wid << 6) | d0;
    if (FINAL) {
      float4 t = *(const float4*)&acc[o];
      t.x = (t.x + a0) * 0.25f;
      t.y = (t.y + a1) * 0.25f;
      t.z = (t.z + a2) * 0.25f;
      t.w = (t.w + a3) * 0.25f;
      *(float4*)&acc[o] = t;
    } else {
      *(unsigned int*)&y[o] = pk_fp8x4(a0, a1, a2, a3);
      float4 t = *(const float4*)&acc[o];
      t.x += a0; t.y += a1; t.z += a2; t.w += a3;
      *(float4*)&acc[o] = t;
    }
  }
}

extern "C" void kernel_launch(void* const* d_in, const int* in_sizes, int n_in,
                              void* d_out, int out_size, void* d_ws, size_t ws_size,
                              hipStream_t stream) {
  const int*   edge_row = (const int*)d_in[0];
  const int*   edge_col = (const int*)d_in[1];
  const float* edge_val = (const float*)d_in[2];
  const float* user_emb = (const float*)d_in[3];
  const float* item_id  = (const float*)d_in[4];
  const float* brand    = (const float*)d_in[5];
  const float* content  = (const float*)d_in[6];
  const float* W        = (const float*)d_in[7];
  const float* bias     = (const float*)d_in[8];
  float* out = (float*)d_out;

  char* ws = (char*)d_ws;
  size_t off = 0;
  auto alloc = [&](size_t bytes) -> void* {
    void* p = ws + off;
    off += (bytes + 255) & ~(size_t)255;
    return p;
  };
  unsigned char* x8_0 = (unsigned char*)alloc((size_t)NN * 64);  // 9.66 MB
  unsigned char* x8_1 = (unsigned char*)alloc((size_t)NN * 64);  // 9.66 MB
  int2*   cv    = (int2*)alloc((size_t)NE * 8);                  // 38.4 MB
  int*    rp    = (int*)alloc((size_t)(NN + 1) * 4);
  int*    rcnt  = (int*)alloc((size_t)NN * 4);                   // 604 KB
  int*    gfill = (int*)alloc((size_t)NN * 4);                   // 604 KB
  int*    bcnt  = (int*)alloc((NBK + 1) * 4);
  int*    bstart= (int*)alloc((NBK + 1) * 4);
  if (off > ws_size) return;

  // --- build CSR: single-level row counting sort ---
  // rcnt and gfill are adjacent: one memset zeroes both.
  hipMemsetAsync(rcnt, 0, (size_t)((char*)gfill - (char*)rcnt) + (size_t)NN * 4,
                 stream);
  const int rhBlocks = (NE + 256 * RH_EPT - 1) / (256 * RH_EPT);  // 2344
  row_hist<<<rhBlocks, 256, 0, stream>>>(edge_row, rcnt);
  bucket_sum<<<NBK, 256, 0, stream>>>(rcnt, bcnt);
  bucket_scan<<<1, 256, 0, stream>>>(bcnt, bstart, rp);
  row_scan<<<NBK, 256, 0, stream>>>(rcnt, bstart, rp);
  const int rsBlocks = (NE + 256 * RS_EPT - 1) / (256 * RS_EPT);  // 2344
  row_scatter<<<rsBlocks, 256, 0, stream>>>(edge_row, edge_col, edge_val, rp,
                                            gfill, cv);

  // --- ego assembly, acc seeding, fp8 conversion, passthrough (fused) ---
  fusion_kernel<<<(NI + 63) / 64, 256, 0, stream>>>(item_id, content, W, bias,
                                                    x8_0, out);
  const int seedTot = UN + BN + IEL;  // 9,664,000 floats
  seed_kernel<<<(seedTot / 4 + 255) / 256, 256, 0, stream>>>(user_emb, brand,
                                                             item_id, x8_0, out);

  // --- 3 propagation layers ---
  const int spmmGrid = (NN + 3) / 4;
  spmm_kernel<false><<<spmmGrid, 256, 0, stream>>>(rp, cv, x8_0, x8_1, out);
  spmm_kernel<false><<<spmmGrid, 256, 0, stream>>>(rp, cv, x8_1, x8_0, out);
  spmm_kernel<true><<<spmmGrid, 256, 0, stream>>>(rp, cv, x8_0, x8_1, out);
}

// Round 5
// 694.407 us; speedup vs baseline: 1.3831x; 1.3831x over previous
//
#include <hip/hip_runtime.h>
#include <hip/hip_fp16.h>

#define NU 100000
#define NI 50000
#define NB 1000
#define NN 151000          // total nodes
#define NE 4800000
#define KDIM 448

#define BROW_BITS 9
#define BROWS 512                       // rows per bucket
#define NBK ((NN + BROWS - 1) / BROWS)  // 295 buckets

typedef float v2f __attribute__((ext_vector_type(2)));

// pack 4 floats -> 4x fp8 e4m3 (OCP on gfx950) in one dword
__device__ __forceinline__ unsigned int pk_fp8x4(float a, float b, float c, float d) {
  int r = 0;
  r = __builtin_amdgcn_cvt_pk_fp8_f32(a, b, r, false);  // low 16
  r = __builtin_amdgcn_cvt_pk_fp8_f32(c, d, r, true);   // high 16
  return (unsigned int)r;
}

// ================= Phase A: bucket histogram (LDS-aggregated) =================
#define HIST_EPT 16
__global__ __launch_bounds__(256) void bucket_hist(const int* __restrict__ erow,
                                                   int* __restrict__ bcnt) {
  __shared__ int lh[NBK];
  for (int i = threadIdx.x; i < NBK; i += 256) lh[i] = 0;
  __syncthreads();
  int base = blockIdx.x * (256 * HIST_EPT) + threadIdx.x;
#pragma unroll
  for (int j = 0; j < HIST_EPT; ++j) {
    int e = base + j * 256;
    if (e < NE) atomicAdd(&lh[erow[e] >> BROW_BITS], 1);
  }
  __syncthreads();
  for (int i = threadIdx.x; i < NBK; i += 256) {
    int c = lh[i];
    if (c) atomicAdd(&bcnt[i], c);
  }
}

// ================= Phase B: scan 295 bucket counts (single block) =================
__global__ __launch_bounds__(256) void bucket_scan(const int* __restrict__ bcnt,
                                                   int* __restrict__ bstart,
                                                   int* __restrict__ rp) {
  __shared__ int sh[256];
  int tid = threadIdx.x;
  int v[2];
  int s = 0;
#pragma unroll
  for (int j = 0; j < 2; ++j) {
    int i = tid * 2 + j;
    v[j] = (i < NBK) ? bcnt[i] : 0;
    s += v[j];
  }
  sh[tid] = s;
  __syncthreads();
  for (int off = 1; off < 256; off <<= 1) {
    int t = (tid >= off) ? sh[tid - off] : 0;
    __syncthreads();
    sh[tid] += t;
    __syncthreads();
  }
  int run = sh[tid] - s;  // exclusive
#pragma unroll
  for (int j = 0; j < 2; ++j) {
    int i = tid * 2 + j;
    if (i < NBK) bstart[i] = run;
    run += v[j];
  }
  if (tid == 255) {
    bstart[NBK] = NE;
    rp[NN] = NE;
  }
}

// ================= Phase C: scatter edges into bucket order =================
// key packs (row&511)<<18 | col  (col < 151000 < 2^18, key < 2^27)
// v2: EPT=8 (2344 blocks) + LDS bucket-grouping stage so the global write
// phase is LINEAR in LDS order -> consecutive lanes write consecutive cvtmp
// addresses (whole-bucket runs back to back). Kills the 3x (R3) / 8x (R4)
// write amplification measured on scattered 8B stores.
#define SC_EPT 8
__global__ __launch_bounds__(256) void bucket_scatter(
    const int* __restrict__ erow, const int* __restrict__ ecol,
    const float* __restrict__ eval, const int* __restrict__ bstart,
    int* __restrict__ gfill, int2* __restrict__ cvtmp) {
  __shared__ int lcnt[NBK];
  __shared__ int lofs[NBK];
  __shared__ int lbase[NBK];
  __shared__ int ssh[256];
  __shared__ int2 ekv[256 * SC_EPT];            // 16 KB staged (key,val)
  __shared__ unsigned short bkid[256 * SC_EPT]; // 4 KB bucket id per slot
  int tid = threadIdx.x;
  for (int i = tid; i < NBK; i += 256) lcnt[i] = 0;
  __syncthreads();
  int base = blockIdx.x * (256 * SC_EPT) + tid;
  int r_[SC_EPT], c_[SC_EPT], rk_[SC_EPT];
  float v_[SC_EPT];
  // phase 1: register-cache edges + per-(block,bucket) ranks
#pragma unroll
  for (int j = 0; j < SC_EPT; ++j) {
    int e = base + j * 256;
    if (e < NE) {
      int r = erow[e];
      r_[j] = r;
      c_[j] = ecol[e];
      v_[j] = eval[e];
      rk_[j] = atomicAdd(&lcnt[r >> BROW_BITS], 1);
    } else {
      r_[j] = -1; c_[j] = 0; v_[j] = 0.f; rk_[j] = 0;
    }
  }
  __syncthreads();
  // phase 2: exclusive scan of lcnt -> lofs (block-local bucket offsets)
  int a0 = (tid * 2 < NBK) ? lcnt[tid * 2] : 0;
  int a1 = (tid * 2 + 1 < NBK) ? lcnt[tid * 2 + 1] : 0;
  int s = a0 + a1;
  ssh[tid] = s;
  __syncthreads();
  for (int off = 1; off < 256; off <<= 1) {
    int t = (tid >= off) ? ssh[tid - off] : 0;
    __syncthreads();
    ssh[tid] += t;
    __syncthreads();
  }
  int excl = ssh[tid] - s;
  if (tid * 2 < NBK) lofs[tid * 2] = excl;
  if (tid * 2 + 1 < NBK) lofs[tid * 2 + 1] = excl + a0;
  // reserve global ranges (one atomic per non-empty bucket per block)
  for (int i = tid; i < NBK; i += 256) {
    int c = lcnt[i];
    lbase[i] = c ? atomicAdd(&gfill[i], c) : 0;
  }
  __syncthreads();
  // phase 3: stage into LDS grouped by bucket
#pragma unroll
  for (int j = 0; j < SC_EPT; ++j) {
    int r = r_[j];
    if (r >= 0) {
      int bk = r >> BROW_BITS;
      int slot = lofs[bk] + rk_[j];
      ekv[slot] = make_int2(((r & (BROWS - 1)) << 18) | c_[j],
                            __float_as_int(v_[j]));
      bkid[slot] = (unsigned short)bk;
    }
  }
  __syncthreads();
  // phase 4: linear LDS walk -> near-contiguous global writes
  int total = ssh[255];  // number of staged edges in this block
#pragma unroll
  for (int j = 0; j < SC_EPT; ++j) {
    int slot = tid + j * 256;
    if (slot < total) {
      int bk = bkid[slot];
      int p = bstart[bk] + lbase[bk] + (slot - lofs[bk]);
      cvtmp[p] = ekv[slot];
    }
  }
}

// ================= Phase D: per-bucket CSR finalize + rp =================
__global__ __launch_bounds__(256) void csr_finalize(
    const int* __restrict__ bstart, const int2* __restrict__ cvtmp,
    int* __restrict__ rp, int2* __restrict__ cv) {
  __shared__ int rcnt[BROWS];
  __shared__ int rex[BROWS];
  __shared__ int ssh[256];
  int b = blockIdx.x;
  int s0 = bstart[b], s1 = bstart[b + 1];
  int tid = threadIdx.x;
  rcnt[tid] = 0;
  rcnt[tid + 256] = 0;
  __syncthreads();
  for (int j = s0 + tid; j < s1; j += 256) atomicAdd(&rcnt[cvtmp[j].x >> 18], 1);
  __syncthreads();
  int v0 = rcnt[2 * tid], v1 = rcnt[2 * tid + 1];
  int tsum = v0 + v1;
  ssh[tid] = tsum;
  __syncthreads();
  for (int off = 1; off < 256; off <<= 1) {
    int t = (tid >= off) ? ssh[tid - off] : 0;
    __syncthreads();
    ssh[tid] += t;
    __syncthreads();
  }
  int excl = ssh[tid] - tsum;
  rex[2 * tid] = excl;
  rex[2 * tid + 1] = excl + v0;
  int row = b * BROWS + 2 * tid;
  if (row < NN) rp[row] = s0 + excl;
  if (row + 1 < NN) rp[row + 1] = s0 + excl + v0;
  rcnt[2 * tid] = 0;
  rcnt[2 * tid + 1] = 0;
  __syncthreads();
  for (int j = s0 + tid; j < s1; j += 256) {
    int2 kv = cvtmp[j];
    int r = kv.x >> 18;
    int c = kv.x & 0x3FFFF;
    int rk = atomicAdd(&rcnt[r], 1);
    cv[s0 + rex[r] + rk] = make_int2(c, kv.y);
  }
}

// ======= fusion GEMM: [NI x 448] @ W^T + bias + leaky; writes fp32 acc-seed + fp8 x =======
__global__ __launch_bounds__(256) void fusion_kernel(
    const float* __restrict__ id_emb, const float* __restrict__ content,
    const float* __restrict__ W, const float* __restrict__ bias,
    unsigned char* __restrict__ x8, float* __restrict__ out) {
  __shared__ float As[16][68];
  __shared__ float Ws[16][68];
  int tid = threadIdx.x;
  int tx = tid & 15;
  int ty = tid >> 4;
  int itemBase = blockIdx.x * 64;
  float acc[4][4] = {};

  int it = tid >> 2;
  int kq = (tid & 3) * 4;

  for (int kb = 0; kb < KDIM; kb += 16) {
    int k = kb + kq;
    int item = itemBase + it;
    int itemc = item < NI ? item : NI - 1;
    float4 a;
    if (k < 64)
      a = *(const float4*)&id_emb[(size_t)itemc * 64 + k];
    else
      a = *(const float4*)&content[(size_t)itemc * 384 + (k - 64)];
    As[kq + 0][it] = a.x; As[kq + 1][it] = a.y; As[kq + 2][it] = a.z; As[kq + 3][it] = a.w;
    float4 w = *(const float4*)&W[(size_t)it * KDIM + k];
    Ws[kq + 0][it] = w.x; Ws[kq + 1][it] = w.y; Ws[kq + 2][it] = w.z; Ws[kq + 3][it] = w.w;
    __syncthreads();
#pragma unroll
    for (int kk = 0; kk < 16; ++kk) {
      float4 af = *(float4*)&As[kk][ty * 4];
      float4 wf = *(float4*)&Ws[kk][tx * 4];
      float av[4] = {af.x, af.y, af.z, af.w};
      float wv[4] = {wf.x, wf.y, wf.z, wf.w};
#pragma unroll
      for (int m = 0; m < 4; ++m)
#pragma unroll
        for (int n = 0; n < 4; ++n) acc[m][n] += av[m] * wv[n];
    }
    __syncthreads();
  }

  int d0 = tx * 4;
  float4 bb = *(const float4*)&bias[d0];
#pragma unroll
  for (int m = 0; m < 4; ++m) {
    int item = itemBase + ty * 4 + m;
    if (item >= NI) continue;
    float4 o;
    float t;
    t = acc[m][0] + bb.x; o.x = t >= 0.f ? t : 0.01f * t;
    t = acc[m][1] + bb.y; o.y = t >= 0.f ? t : 0.01f * t;
    t = acc[m][2] + bb.z; o.z = t >= 0.f ? t : 0.01f * t;
    t = acc[m][3] + bb.w; o.w = t >= 0.f ? t : 0.01f * t;
    size_t ofs = (size_t)(NU + item) * 64 + d0;
    *(float4*)&out[ofs] = o;                       // fp32 acc seed
    *(unsigned int*)&x8[ofs] = pk_fp8x4(o.x, o.y, o.z, o.w);
  }
}

// ======= seed: user/brand -> acc seed + fp8 x; user/item passthrough copies =======
#define UN (NU * 64)     // 6400000
#define BN (NB * 64)     // 64000
#define IEL (NI * 64)    // 3200000
__global__ __launch_bounds__(256) void seed_kernel(
    const float* __restrict__ user_emb, const float* __restrict__ brand,
    const float* __restrict__ item_id, unsigned char* __restrict__ x8,
    float* __restrict__ out) {
  int idx = (blockIdx.x * 256 + threadIdx.x) * 4;
  if (idx < UN) {
    float4 f = *(const float4*)&user_emb[idx];
    *(float4*)&out[idx] = f;                         // acc seed
    *(float4*)&out[(size_t)NN * 64 + idx] = f;       // user passthrough
    *(unsigned int*)&x8[idx] = pk_fp8x4(f.x, f.y, f.z, f.w);
  } else if (idx < UN + BN) {
    int k = idx - UN;
    float4 f = *(const float4*)&brand[k];
    int o = (NU + NI) * 64 + k;
    *(float4*)&out[o] = f;                           // acc seed
    *(unsigned int*)&x8[o] = pk_fp8x4(f.x, f.y, f.z, f.w);
  } else if (idx < UN + BN + IEL) {
    int k = idx - (UN + BN);
    float4 f = *(const float4*)&item_id[k];
    *(float4*)&out[(size_t)(NN + NU) * 64 + k] = f;  // item_id passthrough
  }
}

// ======= SpMM: 1 wave/row, 4x16-lane groups, 4B fp8 gathers (64B/edge) =======
template <bool FINAL>
__global__ __launch_bounds__(256) void spmm_kernel(
    const int* __restrict__ rp, const int2* __restrict__ cv,
    const unsigned char* __restrict__ x, unsigned char* __restrict__ y,
    float* __restrict__ acc) {
  int wid = blockIdx.x * 4 + (threadIdx.x >> 6);
  if (wid >= NN) return;
  int lane = threadIdx.x & 63;
  int grp = lane >> 4;          // 0..3: edge group (stride-4 edge walk)
  int d0 = (lane & 15) << 2;    // 4 dims owned per lane
  const unsigned char* __restrict__ xb = x + d0;
  int beg = rp[wid], end = rp[wid + 1];
  float a0 = 0.f, a1 = 0.f, a2 = 0.f, a3 = 0.f;
  float b0 = 0.f, b1 = 0.f, b2 = 0.f, b3 = 0.f;
  int j = beg + grp;
  // main: 4 edges per group per iter (16 edges/wave); cv[j] is 16-lane-uniform
  // -> single broadcast request; gather is 4B/lane = 64B/row segment.
  for (; j + 12 < end; j += 16) {
    int2 p0 = cv[j];
    int2 p1 = cv[j + 4];
    int2 p2 = cv[j + 8];
    int2 p3 = cv[j + 12];
    unsigned int h0 = *(const unsigned int*)(xb + ((size_t)p0.x << 6));
    unsigned int h1 = *(const unsigned int*)(xb + ((size_t)p1.x << 6));
    unsigned int h2 = *(const unsigned int*)(xb + ((size_t)p2.x << 6));
    unsigned int h3 = *(const unsigned int*)(xb + ((size_t)p3.x << 6));
    float v0 = __int_as_float(p0.y);
    float v1 = __int_as_float(p1.y);
    float v2 = __int_as_float(p2.y);
    float v3 = __int_as_float(p3.y);
    v2f f;
    f = __builtin_amdgcn_cvt_pk_f32_fp8(h0, false); a0 += v0 * f.x; a1 += v0 * f.y;
    f = __builtin_amdgcn_cvt_pk_f32_fp8(h0, true);  a2 += v0 * f.x; a3 += v0 * f.y;
    f = __builtin_amdgcn_cvt_pk_f32_fp8(h1, false); b0 += v1 * f.x; b1 += v1 * f.y;
    f = __builtin_amdgcn_cvt_pk_f32_fp8(h1, true);  b2 += v1 * f.x; b3 += v1 * f.y;
    f = __builtin_amdgcn_cvt_pk_f32_fp8(h2, false); a0 += v2 * f.x; a1 += v2 * f.y;
    f = __builtin_amdgcn_cvt_pk_f32_fp8(h2, true);  a2 += v2 * f.x; a3 += v2 * f.y;
    f = __builtin_amdgcn_cvt_pk_f32_fp8(h3, false); b0 += v3 * f.x; b1 += v3 * f.y;
    f = __builtin_amdgcn_cvt_pk_f32_fp8(h3, true);  b2 += v3 * f.x; b3 += v3 * f.y;
  }
  for (; j < end; j += 4) {  // tail: <=3 iters per group
    int2 p = cv[j];
    unsigned int h = *(const unsigned int*)(xb + ((size_t)p.x << 6));
    float v = __int_as_float(p.y);
    v2f f;
    f = __builtin_amdgcn_cvt_pk_f32_fp8(h, false); a0 += v * f.x; a1 += v * f.y;
    f = __builtin_amdgcn_cvt_pk_f32_fp8(h, true);  a2 += v * f.x; a3 += v * f.y;
  }
  a0 += b0; a1 += b1; a2 += b2; a3 += b3;
  // reduce the 4 groups (epilogue only)
  a0 += __shfl_xor(a0, 16); a1 += __shfl_xor(a1, 16);
  a2 += __shfl_xor(a2, 16); a3 += __shfl_xor(a3, 16);
  a0 += __shfl_xor(a0, 32); a1 += __shfl_xor(a1, 32);
  a2 += __shfl_xor(a2, 32); a3 += __shfl_xor(a3, 32);
  if (lane < 16) {
    int o = (wid << 6) | d0;
    if (FINAL) {
      float4 t = *(const float4*)&acc[o];
      t.x = (t.x + a0) * 0.25f;
      t.y = (t.y + a1) * 0.25f;
      t.z = (t.z + a2) * 0.25f;
      t.w = (t.w + a3) * 0.25f;
      *(float4*)&acc[o] = t;
    } else {
      *(unsigned int*)&y[o] = pk_fp8x4(a0, a1, a2, a3);
      float4 t = *(const float4*)&acc[o];
      t.x += a0; t.y += a1; t.z += a2; t.w += a3;
      *(float4*)&acc[o] = t;
    }
  }
}

extern "C" void kernel_launch(void* const* d_in, const int* in_sizes, int n_in,
                              void* d_out, int out_size, void* d_ws, size_t ws_size,
                              hipStream_t stream) {
  const int*   edge_row = (const int*)d_in[0];
  const int*   edge_col = (const int*)d_in[1];
  const float* edge_val = (const float*)d_in[2];
  const float* user_emb = (const float*)d_in[3];
  const float* item_id  = (const float*)d_in[4];
  const float* brand    = (const float*)d_in[5];
  const float* content  = (const float*)d_in[6];
  const float* W        = (const float*)d_in[7];
  const float* bias     = (const float*)d_in[8];
  float* out = (float*)d_out;

  char* ws = (char*)d_ws;
  size_t off = 0;
  auto alloc = [&](size_t bytes) -> void* {
    void* p = ws + off;
    off += (bytes + 255) & ~(size_t)255;
    return p;
  };
  unsigned char* x8_0 = (unsigned char*)alloc((size_t)NN * 64);  // 9.66 MB
  unsigned char* x8_1 = (unsigned char*)alloc((size_t)NN * 64);  // 9.66 MB
  int2*   cvtmp = (int2*)alloc((size_t)NE * 8);                  // 38.4 MB
  int2*   cv    = (int2*)alloc((size_t)NE * 8);                  // 38.4 MB
  int*    rp    = (int*)alloc((size_t)(NN + 1) * 4);
  int*    bcnt  = (int*)alloc((NBK + 1) * 4);
  int*    bstart= (int*)alloc((NBK + 1) * 4);
  int*    gfill = (int*)alloc((NBK + 1) * 4);
  if (off > ws_size) return;

  // --- build CSR via two-level counting sort ---
  // bcnt/bstart/gfill contiguous: one memset covers all (bstart is fully
  // overwritten by bucket_scan before use).
  hipMemsetAsync(bcnt, 0, (size_t)((char*)gfill - (char*)bcnt) + (NBK + 1) * 4,
                 stream);
  const int histBlocks = (NE + 256 * HIST_EPT - 1) / (256 * HIST_EPT);
  bucket_hist<<<histBlocks, 256, 0, stream>>>(edge_row, bcnt);
  bucket_scan<<<1, 256, 0, stream>>>(bcnt, bstart, rp);
  const int scBlocks = (NE + 256 * SC_EPT - 1) / (256 * SC_EPT);  // 2344
  bucket_scatter<<<scBlocks, 256, 0, stream>>>(edge_row, edge_col, edge_val,
                                               bstart, gfill, cvtmp);
  csr_finalize<<<NBK, 256, 0, stream>>>(bstart, cvtmp, rp, cv);

  // --- ego assembly, acc seeding, fp8 conversion, passthrough (fused) ---
  fusion_kernel<<<(NI + 63) / 64, 256, 0, stream>>>(item_id, content, W, bias,
                                                    x8_0, out);
  const int seedTot = UN + BN + IEL;  // 9,664,000 floats
  seed_kernel<<<(seedTot / 4 + 255) / 256, 256, 0, stream>>>(user_emb, brand,
                                                             item_id, x8_0, out);

  // --- 3 propagation layers ---
  const int spmmGrid = (NN + 3) / 4;
  spmm_kernel<false><<<spmmGrid, 256, 0, stream>>>(rp, cv, x8_0, x8_1, out);
  spmm_kernel<false><<<spmmGrid, 256, 0, stream>>>(rp, cv, x8_1, x8_0, out);
  spmm_kernel<true><<<spmmGrid, 256, 0, stream>>>(rp, cv, x8_0, x8_1, out);
}